// Round 4
// baseline (1242.505 us; speedup 1.0000x reference)
//
#include <hip/hip_runtime.h>
#include <hip/hip_bf16.h>
#include <cstdint>
#include <cstddef>

#define T_TOK 8192
#define DIM   1024
#define HID   2752
#define HID2  (2 * HID)               // 5504 merged W1|W3 rows
#define NE    8
#define NKTOP 2
#define NPAIR (T_TOK * NKTOP)         // 16384 routed pairs
#define NROW  (NPAIR + T_TOK)         // 24576 rows incl shared group
#define BM    256
#define MAXMB (NPAIR / BM + NE + T_TOK / BM)   // 64+8+32 = 104 (13 per XCD)
#define CPX   (MAXMB / 8)
#define N1BLK ((HID2 + 255) / 256)    // 22

using bf16  = __hip_bfloat16;
using frag8 = __attribute__((ext_vector_type(8))) short;   // 8 bf16 (4 VGPRs)
using f32x4 = __attribute__((ext_vector_type(4))) float;   // MFMA accumulator

struct alignas(8) bf16x4_s { bf16 v[4]; };

__device__ __forceinline__ void gload_lds16(const void* g, void* lds) {
  __builtin_amdgcn_global_load_lds(
      (const __attribute__((address_space(1))) unsigned int*)g,
      (__attribute__((address_space(3))) unsigned int*)lds, 16, 0, 0);
}

__device__ __forceinline__ float b2f(short s) {
  union { float f; unsigned u; } x;
  x.u = ((unsigned)(unsigned short)s) << 16;
  return x.f;
}

// ---------------- gating + x->bf16 conversion (fused) ----------------
// 256 blocks x 4 waves; wave handles tokens strided by 1024. While computing
// the 8 logits it also writes the token's bf16 row (x is read exactly once).
__global__ void k_gate2(const float* __restrict__ x, const float* __restrict__ gw,
                        bf16* __restrict__ xb,
                        int* __restrict__ tke, float* __restrict__ tkw,
                        int* __restrict__ counts) {
  __shared__ int lcnt[NE];
  int tid = threadIdx.x;
  if (tid < NE) lcnt[tid] = 0;
  __syncthreads();
  int lane = tid & 63, wid = tid >> 6;
  int wglob = blockIdx.x * 4 + wid;
  for (int t = wglob; t < T_TOK; t += 1024) {
    float acc[NE];
#pragma unroll
    for (int e = 0; e < NE; ++e) acc[e] = 0.f;
#pragma unroll
    for (int it = 0; it < 4; ++it) {
      int d = it * 256 + lane * 4;
      float4 xv = *(const float4*)&x[(size_t)t * DIM + d];
      bf16x4_s o;
      o.v[0] = __float2bfloat16(xv.x);
      o.v[1] = __float2bfloat16(xv.y);
      o.v[2] = __float2bfloat16(xv.z);
      o.v[3] = __float2bfloat16(xv.w);
      *(bf16x4_s*)&xb[(size_t)t * DIM + d] = o;
#pragma unroll
      for (int e = 0; e < NE; ++e) {
        float4 gv = *(const float4*)&gw[(size_t)e * DIM + d];
        acc[e] += xv.x * gv.x + xv.y * gv.y + xv.z * gv.z + xv.w * gv.w;
      }
    }
#pragma unroll
    for (int e = 0; e < NE; ++e)
#pragma unroll
      for (int off = 32; off > 0; off >>= 1)
        acc[e] += __shfl_xor(acc[e], off, 64);
    if (lane == 0) {
      float mx = acc[0];
#pragma unroll
      for (int e = 1; e < NE; ++e) mx = fmaxf(mx, acc[e]);
      float p[NE], s = 0.f;
#pragma unroll
      for (int e = 0; e < NE; ++e) { p[e] = expf(acc[e] - mx); s += p[e]; }
      float inv = 1.f / s;
#pragma unroll
      for (int e = 0; e < NE; ++e) p[e] *= inv;
      int e0 = 0;
#pragma unroll
      for (int e = 1; e < NE; ++e) if (p[e] > p[e0]) e0 = e;
      int e1 = (e0 == 0) ? 1 : 0;
#pragma unroll
      for (int e = 0; e < NE; ++e) if (e != e0 && p[e] > p[e1]) e1 = e;
      tke[t * 2 + 0] = e0;  tkw[t * 2 + 0] = p[e0];
      tke[t * 2 + 1] = e1;  tkw[t * 2 + 1] = p[e1];
      atomicAdd(&lcnt[e0], 1);
      atomicAdd(&lcnt[e1], 1);
    }
  }
  __syncthreads();
  if (tid < NE) atomicAdd(&counts[tid * 16], lcnt[tid]);
}

// ---------------- deterministic pair placement ----------------
__global__ void k_pcount(const int* __restrict__ tke, int* __restrict__ bcnt) {
  __shared__ int lcnt[NE];
  int tid = threadIdx.x;
  if (tid < NE) lcnt[tid] = 0;
  __syncthreads();
  int e = tke[blockIdx.x * 256 + tid];
  atomicAdd(&lcnt[e], 1);
  __syncthreads();
  if (tid < NE) bcnt[blockIdx.x * NE + tid] = lcnt[tid];
}

__global__ void k_pscan(const int* __restrict__ counts, const int* __restrict__ bcnt,
                        int* __restrict__ offs, int* __restrict__ bbase,
                        int* __restrict__ mtab) {
  if (threadIdx.x == 0) {
    int s = 0;
    for (int e = 0; e < NE; ++e) { offs[e] = s; s += counts[e * 16]; }
    offs[NE] = s;                 // 16384 = start of shared group
    offs[NE + 1] = s + T_TOK;     // 24576
    int run[NE];
    for (int e = 0; e < NE; ++e) run[e] = offs[e];
    for (int b = 0; b < NPAIR / 256; ++b)
      for (int e = 0; e < NE; ++e) { bbase[b * NE + e] = run[e]; run[e] += bcnt[b * NE + e]; }
    int sl = 0;
    for (int e = 0; e < NE + 1; ++e) {       // 9 groups incl shared
      int cnt = offs[e + 1] - offs[e];
      int nb = (cnt + BM - 1) / BM;
      for (int b = 0; b < nb; ++b) mtab[sl++] = (e << 16) | b;
    }
    for (; sl < MAXMB; ++sl) mtab[sl] = -1;
  }
}

// pair placement (blocks 0..63) + shared-group identity init (blocks 64..95).
// also writes inverse map inv[pair i] = pos (for the reduce kernel)
__global__ void k_place(const int* __restrict__ tke, const float* __restrict__ tkw,
                        const int* __restrict__ bbase,
                        int* __restrict__ ptok, float* __restrict__ pw,
                        int* __restrict__ inv) {
  __shared__ int wcnt[4][NE];
  int tid = threadIdx.x;
  if (blockIdx.x >= NPAIR / 256) {           // identity tail (was k_ident)
    int i = (blockIdx.x - NPAIR / 256) * 256 + tid;
    ptok[NPAIR + i] = i;
    pw[NPAIR + i]   = 1.f;
    return;
  }
  int lane = tid & 63, w = tid >> 6;
  int i = blockIdx.x * 256 + tid;
  int e = tke[i];
  unsigned long long lower = (lane == 63) ? ~0ull >> 1 : ((1ull << lane) - 1);
  int rank = 0;
#pragma unroll
  for (int ex = 0; ex < NE; ++ex) {
    unsigned long long m = __ballot(e == ex);
    if (e == ex) rank = __popcll(m & lower);
    if (lane == 0) wcnt[w][ex] = __popcll(m);
  }
  __syncthreads();
  int wb = 0;
  for (int w2 = 0; w2 < w; ++w2) wb += wcnt[w2][e];
  int pos = bbase[blockIdx.x * NE + e] + wb + rank;
  ptok[pos] = i >> 1;
  pw[pos]   = tkw[i];
  inv[i]    = pos;
}

// ---------------- weight transpose-convert ----------------
// in fp32 [K][N] -> out bf16 rows (B^T layout) with optional merged-W13 row remap.
// mode 0: orow = h;  mode 1 (W1): orow = (h>>5)*64 + (h&31);  mode 2 (W3): +32
__device__ __forceinline__ void wt_tile2(const float* __restrict__ in, bf16* __restrict__ out,
                                         int K, int N, int nb, int kb, int mode) {
  __shared__ bf16 tile[64][65];
  int c16 = threadIdx.x >> 4;
  int r16 = threadIdx.x & 15;
#pragma unroll
  for (int it = 0; it < 4; ++it) {
    int k = it * 16 + c16;
    int n = r16 * 4;
    float4 v = *(const float4*)&in[(size_t)(kb + k) * N + nb + n];
    tile[n + 0][k] = __float2bfloat16(v.x);
    tile[n + 1][k] = __float2bfloat16(v.y);
    tile[n + 2][k] = __float2bfloat16(v.z);
    tile[n + 3][k] = __float2bfloat16(v.w);
  }
  __syncthreads();
#pragma unroll
  for (int it = 0; it < 4; ++it) {
    int n = it * 16 + c16;
    int k = r16 * 4;
    int h = nb + n;
    int orow = (mode == 0) ? h : ((h >> 5) * 64 + (h & 31) + (mode == 2 ? 32 : 0));
    bf16x4_s o;
    o.v[0] = tile[n][k + 0];
    o.v[1] = tile[n][k + 1];
    o.v[2] = tile[n][k + 2];
    o.v[3] = tile[n][k + 3];
    *(bf16x4_s*)&out[(size_t)orow * K + kb + k] = o;
  }
}

// one launch, 27 matrices: y 0..7 w1, 8..15 w3, 16..23 w2, 24 sw1, 25 sw3, 26 sw2
__global__ void k_wt_all(const float* __restrict__ w1, const float* __restrict__ w2,
                         const float* __restrict__ w3, const float* __restrict__ sw1,
                         const float* __restrict__ sw2, const float* __restrict__ sw3,
                         bf16* __restrict__ wt13, bf16* __restrict__ wt2) {
  int m = blockIdx.y;
  const size_t SZ = (size_t)DIM * HID;
  const size_t S13 = (size_t)HID2 * DIM;
  const float* src; bf16* dst; int K, N, mode;
  if (m < 8)       { src = w1 + (size_t)m * SZ;        dst = wt13 + (size_t)m * S13;        K = DIM; N = HID; mode = 1; }
  else if (m < 16) { src = w3 + (size_t)(m - 8) * SZ;  dst = wt13 + (size_t)(m - 8) * S13;  K = DIM; N = HID; mode = 2; }
  else if (m < 24) { src = w2 + (size_t)(m - 16) * SZ; dst = wt2 + (size_t)(m - 16) * SZ;   K = HID; N = DIM; mode = 0; }
  else if (m == 24){ src = sw1; dst = wt13 + 8 * S13; K = DIM; N = HID; mode = 1; }
  else if (m == 25){ src = sw3; dst = wt13 + 8 * S13; K = DIM; N = HID; mode = 2; }
  else             { src = sw2; dst = wt2 + 8 * SZ;   K = HID; N = DIM; mode = 0; }
  int nx = N / 64;
  int bx = blockIdx.x;
  wt_tile2(src, dst, K, N, (bx % nx) * 64, (bx / nx) * 64, mode);
}

// ---------------- 256x256x64 grouped GEMM core (R11: reg-A-from-global, LDS-B) ----------------
// Theory: R6's wall ~= MFMA cycles + LDS cycles (near-zero overlap; LDS pipe is
// binding at 260 KB/tile/CU). A was 4x-redundantly ds_read by waves AND DMA-written.
// R11 loads A fragments per-lane DIRECTLY from global into registers:
//   frag bytes = Abase + aoff[qm][f] + t*128 + ks*64, aoff = row_off + kl*16
// (byte-identical data to the swizzled-LDS path). LDS now holds only B
// (dbuf 2x32KB = 64KB). Per tile: 1 vmcnt(0) + 1 barrier (B dbuf safety);
// A-register deps are compiler-waited (no inline-asm/MFMA hazard, rule #18 n/a).
// Slot safety: stage(t+1) into slot ns after t's entry barrier; ns last read at
// t-1, and those ds_reads complete before t-1's MFMAs which precede t's barrier.
// Accumulation order per acc element identical to R6 -> bit-identical numerics.
// [Ledger: R7 fences, R8 phases, R9 launch_bounds(512,4) all regressed.
//  launch_bounds MUST stay (512,2); acc=128 regs pins 1 block/CU regardless.]
template <int LDK, int NT>
__device__ __forceinline__ void gemm256g(const char* Abase, const unsigned (&aoff)[2][4],
                                         const bf16* gB0, char* smem, int tid,
                                         f32x4 (&acc)[8][4]) {
  const int wave = tid >> 6, lane = tid & 63;
  const int wn = wave & 3;
  const int fr = lane & 15, kl = lane >> 4;

  auto stageB = [&](int sel, int k0, int q) {
    gload_lds16(gB0 + (size_t)q * 64 * LDK + k0,
                smem + sel * 32768 + q * 8192 + wave * 1024);
  };

  frag8 af[4][2], bf0[2][2], bf1[2][2];

  auto rdB = [&](frag8 (&d)[2][2], const char* bB, int qn) {
#pragma unroll
    for (int f = 0; f < 2; ++f) {
      int row = wn * 64 + qn * 32 + f * 16 + fr;
#pragma unroll
      for (int ks = 0; ks < 2; ++ks)
        d[f][ks] = *(const frag8*)(bB + row * 128 + (((ks * 4 + kl) ^ (row & 7)) << 4));
    }
  };
  auto ldA = [&](int qm, int t) {
#pragma unroll
    for (int f = 0; f < 4; ++f) {
      const char* p = Abase + aoff[qm][f] + t * 128;
      af[f][0] = *(const frag8*)p;           // k-chunks kl, kl+4 (ks*64 apart)
      af[f][1] = *(const frag8*)(p + 64);
    }
  };

  // 32-MFMA cluster: rows MO..MO+3 (x16), all 4 N-subtiles, K=64
#define MF32(MO)                                                                         \
  __builtin_amdgcn_s_setprio(1);                                                         \
  _Pragma("unroll") for (int m_ = 0; m_ < 4; ++m_) {                                     \
    _Pragma("unroll") for (int ks_ = 0; ks_ < 2; ++ks_) {                                \
      acc[(MO) + m_][0] = __builtin_amdgcn_mfma_f32_16x16x32_bf16(                       \
          af[m_][ks_], bf0[0][ks_], acc[(MO) + m_][0], 0, 0, 0);                         \
      acc[(MO) + m_][1] = __builtin_amdgcn_mfma_f32_16x16x32_bf16(                       \
          af[m_][ks_], bf0[1][ks_], acc[(MO) + m_][1], 0, 0, 0);                         \
      acc[(MO) + m_][2] = __builtin_amdgcn_mfma_f32_16x16x32_bf16(                       \
          af[m_][ks_], bf1[0][ks_], acc[(MO) + m_][2], 0, 0, 0);                         \
      acc[(MO) + m_][3] = __builtin_amdgcn_mfma_f32_16x16x32_bf16(                       \
          af[m_][ks_], bf1[1][ks_], acc[(MO) + m_][3], 0, 0, 0);                         \
    }                                                                                    \
  }                                                                                      \
  __builtin_amdgcn_s_setprio(0);

  // prologue: stage tile-0 B
  stageB(0, 0, 0); stageB(0, 0, 1); stageB(0, 0, 2); stageB(0, 0, 3);

#pragma unroll 1
  for (int t = 0; t < NT; ++t) {
    const char* bCur = smem + (t & 1) * 32768;

    asm volatile("s_waitcnt vmcnt(0)" ::: "memory");   // t's B stages landed
    __builtin_amdgcn_s_barrier();
    asm volatile("" ::: "memory");

    if (t + 1 < NT) {
      const int ns = (t + 1) & 1, kn = (t + 1) * 64;
      stageB(ns, kn, 0); stageB(ns, kn, 1); stageB(ns, kn, 2); stageB(ns, kn, 3);
    }

    ldA(0, t);
    rdB(bf0, bCur, 0);
    rdB(bf1, bCur, 1);
    MF32(0)
    ldA(1, t);
    MF32(4)
  }
#undef MF32
}

// ---------------- FFN1 grouped: h = silu(g)*u, merged wt13 ----------------
__global__ __launch_bounds__(512, 2)
void k_ffn1g(const bf16* __restrict__ xb, const bf16* __restrict__ wt13,
             bf16* __restrict__ hbuf, const int* __restrict__ ptok,
             const int* __restrict__ offs, const int* __restrict__ mtab) {
  extern __shared__ char smem[];
  int bx = (blockIdx.x & 7) * CPX + (blockIdx.x >> 3);   // XCD-chunked
  int entry = mtab[bx];
  if (entry < 0) return;
  int e = entry >> 16;
  int base = offs[e], nloc = offs[e + 1] - base;
  int m0 = (entry & 0xffff) * BM, n0 = blockIdx.y * 256;
  const bf16* wB = wt13 + (size_t)e * HID2 * DIM;
  bf16* hA = hbuf + (size_t)base * HID;

  int tid = threadIdx.x;
  int rr = tid >> 3, cc = tid & 7;
  int br = n0 + rr; if (br > HID2 - 1) br = HID2 - 1;
  const bf16* gB0 = wB + (size_t)br * DIM + (cc ^ (rr & 7)) * 8;

  int lane = tid & 63, wave = tid >> 6;
  int wm = wave >> 2, fr = lane & 15, kl = lane >> 4;
  unsigned aoff[2][4];
#pragma unroll
  for (int qm = 0; qm < 2; ++qm)
#pragma unroll
    for (int f = 0; f < 4; ++f) {
      int lr = m0 + wm * 128 + qm * 64 + f * 16 + fr;
      if (lr > nloc - 1) lr = nloc - 1;
      aoff[qm][f] = (unsigned)ptok[base + lr] * (DIM * 2) + kl * 16;
    }

  f32x4 acc[8][4];
  f32x4 zero = {0.f, 0.f, 0.f, 0.f};
#pragma unroll
  for (int a = 0; a < 8; ++a)
#pragma unroll
    for (int b = 0; b < 4; ++b) acc[a][b] = zero;

  gemm256g<DIM, DIM / 64>((const char*)xb, aoff, gB0, smem, tid, acc);

  int wn = wave & 3;
  int rj = (lane >> 4) * 4;
  int c0 = n0 + wn * 64;
#pragma unroll
  for (int m = 0; m < 8; ++m) {
#pragma unroll
    for (int j = 0; j < 4; ++j) {
      int rl = m0 + wm * 128 + m * 16 + rj + j;
      if (rl >= nloc) continue;
      bf16* hrow = hA + (size_t)rl * HID;
#pragma unroll
      for (int n = 0; n < 2; ++n) {
        int hcol = (c0 >> 1) + n * 16 + fr;
        if (hcol >= HID) continue;
        float g = acc[m][n][j], u = acc[m][n + 2][j];
        hrow[hcol] = __float2bfloat16(g / (1.f + __expf(-g)) * u);
      }
    }
  }
}

// ---------------- FFN2 grouped ----------------
// ATOMIC=1: out[tok] += w*(h@W2) via atomicAdd (fallback).
// ATOMIC=0: pbuf[base+rl] = bf16(w*(h@W2)) plain stores; reduced by k_reduce.
template <int ATOMIC>
__global__ __launch_bounds__(512, 2)
void k_ffn2g(const bf16* __restrict__ hbuf, const bf16* __restrict__ wt2,
             float* __restrict__ out, bf16* __restrict__ pbuf,
             const int* __restrict__ ptok, const float* __restrict__ pw,
             const int* __restrict__ offs, const int* __restrict__ mtab) {
  extern __shared__ char smem[];
  int bx = (blockIdx.x & 7) * CPX + (blockIdx.x >> 3);
  int entry = mtab[bx];
  if (entry < 0) return;
  int e = entry >> 16;
  int base = offs[e], nloc = offs[e + 1] - base;
  int m0 = (entry & 0xffff) * BM, n0 = blockIdx.y * 256;
  const bf16* wB = wt2 + (size_t)e * DIM * HID;
  const bf16* hA = hbuf + (size_t)base * HID;

  int tid = threadIdx.x;
  int rr = tid >> 3, cc = tid & 7;
  const bf16* gB0 = wB + (size_t)(n0 + rr) * HID + (cc ^ (rr & 7)) * 8;

  int lane = tid & 63, wave = tid >> 6;
  int wm = wave >> 2, fr = lane & 15, kl = lane >> 4;
  unsigned aoff[2][4];
#pragma unroll
  for (int qm = 0; qm < 2; ++qm)
#pragma unroll
    for (int f = 0; f < 4; ++f) {
      int lr = m0 + wm * 128 + qm * 64 + f * 16 + fr;
      if (lr > nloc - 1) lr = nloc - 1;
      aoff[qm][f] = (unsigned)lr * (HID * 2) + kl * 16;
    }

  f32x4 acc[8][4];
  f32x4 zero = {0.f, 0.f, 0.f, 0.f};
#pragma unroll
  for (int a = 0; a < 8; ++a)
#pragma unroll
    for (int b = 0; b < 4; ++b) acc[a][b] = zero;

  gemm256g<HID, HID / 64>((const char*)hA, aoff, gB0, smem, tid, acc);

  int wn = wave & 3;
  int rj = (lane >> 4) * 4;
#pragma unroll
  for (int m = 0; m < 8; ++m) {
#pragma unroll
    for (int j = 0; j < 4; ++j) {
      int rl = m0 + wm * 128 + m * 16 + rj + j;
      if (rl >= nloc) continue;
      float w = pw[base + rl];
      if (ATOMIC) {
        int tok = ptok[base + rl];
        float* orow = out + (size_t)tok * DIM + n0 + wn * 64 + fr;
#pragma unroll
        for (int n = 0; n < 4; ++n)
          atomicAdd(orow + n * 16, w * acc[m][n][j]);
      } else {
        bf16* prow = pbuf + (size_t)(base + rl) * DIM + n0 + wn * 64 + fr;
#pragma unroll
        for (int n = 0; n < 4; ++n)
          prow[n * 16] = __float2bfloat16(w * acc[m][n][j]);
      }
    }
  }
}

// ---------------- reduce: out[t] = pbuf[inv[2t]] + pbuf[inv[2t+1]] + pbuf[NPAIR+t] ----------------
__global__ void k_reduce(const bf16* __restrict__ pbuf, const int* __restrict__ inv,
                         float* __restrict__ out) {
  int t = blockIdx.x * 2 + (threadIdx.x >> 7);      // 2 tokens per 256-thread block
  int c = (threadIdx.x & 127) * 8;                  // 8 cols per thread
  int p0 = inv[t * 2], p1 = inv[t * 2 + 1];
  frag8 v0 = *(const frag8*)&pbuf[(size_t)p0 * DIM + c];
  frag8 v1 = *(const frag8*)&pbuf[(size_t)p1 * DIM + c];
  frag8 v2 = *(const frag8*)&pbuf[(size_t)(NPAIR + t) * DIM + c];
  float r[8];
#pragma unroll
  for (int j = 0; j < 8; ++j) r[j] = b2f(v0[j]) + b2f(v1[j]) + b2f(v2[j]);
  float4 lo = {r[0], r[1], r[2], r[3]};
  float4 hi = {r[4], r[5], r[6], r[7]};
  *(float4*)&out[(size_t)t * DIM + c]     = lo;
  *(float4*)&out[(size_t)t * DIM + c + 4] = hi;
}

extern "C" void kernel_launch(void* const* d_in, const int* in_sizes, int n_in,
                              void* d_out, int out_size, void* d_ws, size_t ws_size,
                              hipStream_t stream) {
  const float* x   = (const float*)d_in[0];
  const float* gw  = (const float*)d_in[1];
  const float* w1  = (const float*)d_in[2];
  const float* w2  = (const float*)d_in[3];
  const float* w3  = (const float*)d_in[4];
  const float* sw1 = (const float*)d_in[5];
  const float* sw2 = (const float*)d_in[6];
  const float* sw3 = (const float*)d_in[7];
  float* out = (float*)d_out;

  char* ws = (char*)d_ws;
  size_t off = 0;
  auto alloc = [&](size_t bytes) -> void* {
    void* p = ws + off;
    off += (bytes + 255) & ~(size_t)255;
    return p;
  };
  const size_t SZ  = (size_t)DIM * HID;
  const size_t S13 = (size_t)HID2 * DIM;

  // ---- meta ----
  int*   tke    = (int*)alloc((size_t)NPAIR * 4);
  float* tkw    = (float*)alloc((size_t)NPAIR * 4);
  int*   ptok   = (int*)alloc((size_t)NROW * 4);
  float* pw     = (float*)alloc((size_t)NROW * 4);
  int*   inv    = (int*)alloc((size_t)NPAIR * 4);
  int*   counts = (int*)alloc(16 * NE * 4);
  int*   offs   = (int*)alloc((NE + 2) * 4);
  int*   bcnt   = (int*)alloc((size_t)(NPAIR / 256) * NE * 4);
  int*   bbase  = (int*)alloc((size_t)(NPAIR / 256) * NE * 4);
  int*   mtab   = (int*)alloc(MAXMB * 4);
  bf16*  xb     = (bf16*)alloc((size_t)T_TOK * DIM * 2);

  // ---- grouped layout (~305 MB; proven to fit in rounds 2-7) ----
  bf16* wt13 = (bf16*)alloc(9 * S13 * 2);
  bf16* wt2b = (bf16*)alloc(9 * SZ * 2);
  bf16* hbuf = (bf16*)alloc((size_t)NROW * HID * 2);
  if (off > ws_size) return;   // visible failure signature

  // optional partial-sum buffer (+50 MB); fallback to atomic path if it won't fit
  bf16* pbuf = (bf16*)alloc((size_t)NROW * DIM * 2);
  bool usePbuf = (off <= ws_size);

  hipFuncSetAttribute((const void*)k_ffn1g, hipFuncAttributeMaxDynamicSharedMemorySize, 65536);
  hipFuncSetAttribute((const void*)k_ffn2g<0>, hipFuncAttributeMaxDynamicSharedMemorySize, 65536);
  hipFuncSetAttribute((const void*)k_ffn2g<1>, hipFuncAttributeMaxDynamicSharedMemorySize, 65536);

  // ---- frontend ----
  hipMemsetAsync(counts, 0, 16 * NE * sizeof(int), stream);
  if (!usePbuf)
    hipMemsetAsync(out, 0, (size_t)out_size * sizeof(float), stream);
  k_gate2<<<256, 256, 0, stream>>>(x, gw, xb, tke, tkw, counts);
  k_pcount<<<NPAIR / 256, 256, 0, stream>>>(tke, bcnt);
  k_pscan<<<1, 64, 0, stream>>>(counts, bcnt, offs, bbase, mtab);
  k_place<<<NPAIR / 256 + T_TOK / 256, 256, 0, stream>>>(tke, tkw, bbase, ptok, pw, inv);

  k_wt_all<<<dim3(688, 27), 256, 0, stream>>>(w1, w2, w3, sw1, sw2, sw3, wt13, wt2b);
  k_ffn1g<<<dim3(MAXMB, N1BLK), 512, 65536, stream>>>(xb, wt13, hbuf, ptok, offs, mtab);
  if (usePbuf) {
    k_ffn2g<0><<<dim3(MAXMB, DIM / 256), 512, 65536, stream>>>(hbuf, wt2b, out, pbuf,
                                                               ptok, pw, offs, mtab);
    k_reduce<<<T_TOK / 2, 256, 0, stream>>>(pbuf, inv, out);
  } else {
    k_ffn2g<1><<<dim3(MAXMB, DIM / 256), 512, 65536, stream>>>(hbuf, wt2b, out, pbuf,
                                                               ptok, pw, offs, mtab);
  }
}

// Round 5
// 1225.806 us; speedup vs baseline: 1.0136x; 1.0136x over previous
//
#include <hip/hip_runtime.h>
#include <hip/hip_bf16.h>
#include <cstdint>
#include <cstddef>

#define T_TOK 8192
#define DIM   1024
#define HID   2752
#define HID2  (2 * HID)               // 5504 merged W1|W3 rows
#define NE    8
#define NKTOP 2
#define NPAIR (T_TOK * NKTOP)         // 16384 routed pairs
#define NROW  (NPAIR + T_TOK)         // 24576 rows incl shared group
#define BM    256
#define MAXMB (NPAIR / BM + NE + T_TOK / BM)   // 64+8+32 = 104 (13 per XCD)
#define CPX   (MAXMB / 8)
#define N1BLK ((HID2 + 255) / 256)    // 22

using bf16  = __hip_bfloat16;
using frag8 = __attribute__((ext_vector_type(8))) short;   // 8 bf16 (4 VGPRs)
using f32x4 = __attribute__((ext_vector_type(4))) float;   // MFMA accumulator

struct alignas(8) bf16x4_s { bf16 v[4]; };

__device__ __forceinline__ void gload_lds16(const void* g, void* lds) {
  __builtin_amdgcn_global_load_lds(
      (const __attribute__((address_space(1))) unsigned int*)g,
      (__attribute__((address_space(3))) unsigned int*)lds, 16, 0, 0);
}

__device__ __forceinline__ float b2f(short s) {
  union { float f; unsigned u; } x;
  x.u = ((unsigned)(unsigned short)s) << 16;
  return x.f;
}

// ---------------- gating + x->bf16 conversion (fused) ----------------
__global__ void k_gate2(const float* __restrict__ x, const float* __restrict__ gw,
                        bf16* __restrict__ xb,
                        int* __restrict__ tke, float* __restrict__ tkw,
                        int* __restrict__ counts) {
  __shared__ int lcnt[NE];
  int tid = threadIdx.x;
  if (tid < NE) lcnt[tid] = 0;
  __syncthreads();
  int lane = tid & 63, wid = tid >> 6;
  int wglob = blockIdx.x * 4 + wid;
  for (int t = wglob; t < T_TOK; t += 1024) {
    float acc[NE];
#pragma unroll
    for (int e = 0; e < NE; ++e) acc[e] = 0.f;
#pragma unroll
    for (int it = 0; it < 4; ++it) {
      int d = it * 256 + lane * 4;
      float4 xv = *(const float4*)&x[(size_t)t * DIM + d];
      bf16x4_s o;
      o.v[0] = __float2bfloat16(xv.x);
      o.v[1] = __float2bfloat16(xv.y);
      o.v[2] = __float2bfloat16(xv.z);
      o.v[3] = __float2bfloat16(xv.w);
      *(bf16x4_s*)&xb[(size_t)t * DIM + d] = o;
#pragma unroll
      for (int e = 0; e < NE; ++e) {
        float4 gv = *(const float4*)&gw[(size_t)e * DIM + d];
        acc[e] += xv.x * gv.x + xv.y * gv.y + xv.z * gv.z + xv.w * gv.w;
      }
    }
#pragma unroll
    for (int e = 0; e < NE; ++e)
#pragma unroll
      for (int off = 32; off > 0; off >>= 1)
        acc[e] += __shfl_xor(acc[e], off, 64);
    if (lane == 0) {
      float mx = acc[0];
#pragma unroll
      for (int e = 1; e < NE; ++e) mx = fmaxf(mx, acc[e]);
      float p[NE], s = 0.f;
#pragma unroll
      for (int e = 0; e < NE; ++e) { p[e] = expf(acc[e] - mx); s += p[e]; }
      float inv = 1.f / s;
#pragma unroll
      for (int e = 0; e < NE; ++e) p[e] *= inv;
      int e0 = 0;
#pragma unroll
      for (int e = 1; e < NE; ++e) if (p[e] > p[e0]) e0 = e;
      int e1 = (e0 == 0) ? 1 : 0;
#pragma unroll
      for (int e = 0; e < NE; ++e) if (e != e0 && p[e] > p[e1]) e1 = e;
      tke[t * 2 + 0] = e0;  tkw[t * 2 + 0] = p[e0];
      tke[t * 2 + 1] = e1;  tkw[t * 2 + 1] = p[e1];
      atomicAdd(&lcnt[e0], 1);
      atomicAdd(&lcnt[e1], 1);
    }
  }
  __syncthreads();
  if (tid < NE) atomicAdd(&counts[tid * 16], lcnt[tid]);
}

// ---------------- deterministic pair placement ----------------
__global__ void k_pcount(const int* __restrict__ tke, int* __restrict__ bcnt) {
  __shared__ int lcnt[NE];
  int tid = threadIdx.x;
  if (tid < NE) lcnt[tid] = 0;
  __syncthreads();
  int e = tke[blockIdx.x * 256 + tid];
  atomicAdd(&lcnt[e], 1);
  __syncthreads();
  if (tid < NE) bcnt[blockIdx.x * NE + tid] = lcnt[tid];
}

__global__ void k_pscan(const int* __restrict__ counts, const int* __restrict__ bcnt,
                        int* __restrict__ offs, int* __restrict__ bbase,
                        int* __restrict__ mtab) {
  if (threadIdx.x == 0) {
    int s = 0;
    for (int e = 0; e < NE; ++e) { offs[e] = s; s += counts[e * 16]; }
    offs[NE] = s;                 // 16384 = start of shared group
    offs[NE + 1] = s + T_TOK;     // 24576
    int run[NE];
    for (int e = 0; e < NE; ++e) run[e] = offs[e];
    for (int b = 0; b < NPAIR / 256; ++b)
      for (int e = 0; e < NE; ++e) { bbase[b * NE + e] = run[e]; run[e] += bcnt[b * NE + e]; }
    int sl = 0;
    for (int e = 0; e < NE + 1; ++e) {       // 9 groups incl shared
      int cnt = offs[e + 1] - offs[e];
      int nb = (cnt + BM - 1) / BM;
      for (int b = 0; b < nb; ++b) mtab[sl++] = (e << 16) | b;
    }
    for (; sl < MAXMB; ++sl) mtab[sl] = -1;
  }
}

// pair placement (blocks 0..63) + shared-group identity init (blocks 64..95).
// also writes inverse map inv[pair i] = pos (for the reduce kernel)
__global__ void k_place(const int* __restrict__ tke, const float* __restrict__ tkw,
                        const int* __restrict__ bbase,
                        int* __restrict__ ptok, float* __restrict__ pw,
                        int* __restrict__ inv) {
  __shared__ int wcnt[4][NE];
  int tid = threadIdx.x;
  if (blockIdx.x >= NPAIR / 256) {           // identity tail (was k_ident)
    int i = (blockIdx.x - NPAIR / 256) * 256 + tid;
    ptok[NPAIR + i] = i;
    pw[NPAIR + i]   = 1.f;
    return;
  }
  int lane = tid & 63, w = tid >> 6;
  int i = blockIdx.x * 256 + tid;
  int e = tke[i];
  unsigned long long lower = (lane == 63) ? ~0ull >> 1 : ((1ull << lane) - 1);
  int rank = 0;
#pragma unroll
  for (int ex = 0; ex < NE; ++ex) {
    unsigned long long m = __ballot(e == ex);
    if (e == ex) rank = __popcll(m & lower);
    if (lane == 0) wcnt[w][ex] = __popcll(m);
  }
  __syncthreads();
  int wb = 0;
  for (int w2 = 0; w2 < w; ++w2) wb += wcnt[w2][e];
  int pos = bbase[blockIdx.x * NE + e] + wb + rank;
  ptok[pos] = i >> 1;
  pw[pos]   = tkw[i];
  inv[i]    = pos;
}

// ---------------- weight transpose-convert ----------------
// in fp32 [K][N] -> out bf16 rows (B^T layout) with optional merged-W13 row remap.
// mode 0: orow = h;  mode 1 (W1): orow = (h>>5)*64 + (h&31);  mode 2 (W3): +32
__device__ __forceinline__ void wt_tile2(const float* __restrict__ in, bf16* __restrict__ out,
                                         int K, int N, int nb, int kb, int mode) {
  __shared__ bf16 tile[64][65];
  int c16 = threadIdx.x >> 4;
  int r16 = threadIdx.x & 15;
#pragma unroll
  for (int it = 0; it < 4; ++it) {
    int k = it * 16 + c16;
    int n = r16 * 4;
    float4 v = *(const float4*)&in[(size_t)(kb + k) * N + nb + n];
    tile[n + 0][k] = __float2bfloat16(v.x);
    tile[n + 1][k] = __float2bfloat16(v.y);
    tile[n + 2][k] = __float2bfloat16(v.z);
    tile[n + 3][k] = __float2bfloat16(v.w);
  }
  __syncthreads();
#pragma unroll
  for (int it = 0; it < 4; ++it) {
    int n = it * 16 + c16;
    int k = r16 * 4;
    int h = nb + n;
    int orow = (mode == 0) ? h : ((h >> 5) * 64 + (h & 31) + (mode == 2 ? 32 : 0));
    bf16x4_s o;
    o.v[0] = tile[n][k + 0];
    o.v[1] = tile[n][k + 1];
    o.v[2] = tile[n][k + 2];
    o.v[3] = tile[n][k + 3];
    *(bf16x4_s*)&out[(size_t)orow * K + kb + k] = o;
  }
}

// one launch, 27 matrices: y 0..7 w1, 8..15 w3, 16..23 w2, 24 sw1, 25 sw3, 26 sw2
__global__ void k_wt_all(const float* __restrict__ w1, const float* __restrict__ w2,
                         const float* __restrict__ w3, const float* __restrict__ sw1,
                         const float* __restrict__ sw2, const float* __restrict__ sw3,
                         bf16* __restrict__ wt13, bf16* __restrict__ wt2) {
  int m = blockIdx.y;
  const size_t SZ = (size_t)DIM * HID;
  const size_t S13 = (size_t)HID2 * DIM;
  const float* src; bf16* dst; int K, N, mode;
  if (m < 8)       { src = w1 + (size_t)m * SZ;        dst = wt13 + (size_t)m * S13;        K = DIM; N = HID; mode = 1; }
  else if (m < 16) { src = w3 + (size_t)(m - 8) * SZ;  dst = wt13 + (size_t)(m - 8) * S13;  K = DIM; N = HID; mode = 2; }
  else if (m < 24) { src = w2 + (size_t)(m - 16) * SZ; dst = wt2 + (size_t)(m - 16) * SZ;   K = HID; N = DIM; mode = 0; }
  else if (m == 24){ src = sw1; dst = wt13 + 8 * S13; K = DIM; N = HID; mode = 1; }
  else if (m == 25){ src = sw3; dst = wt13 + 8 * S13; K = DIM; N = HID; mode = 2; }
  else             { src = sw2; dst = wt2 + 8 * SZ;   K = HID; N = DIM; mode = 0; }
  int nx = N / 64;
  int bx = blockIdx.x;
  wt_tile2(src, dst, K, N, (bx % nx) * 64, (bx / nx) * 64, mode);
}

// ---------------- 256x256x64 grouped GEMM core (R12: reg-A, issue-order-fixed) ----------------
// R11's failure: A-loads issued AFTER stageB(t+1) -> compiler's wait for A = vmcnt(0)
// -> drained the B prefetch DMAs mid-tile, exposing ~900cy HBM latency twice/tile
// (16.7% MfmaUtil measured). vmcnt is an ORDERED counter: a wait for op X drains
// everything older than X. Fix = pin VMEM issue order so A is always OLDER than
// the B stages that must stay in flight:
//   ldA(qm0) | stageB01 | rdB+MF32(0)  <- wait vmcnt(2): af landed, B01 flies
//   ldA(qm1) | stageB23 | MF32(4)      <- wait vmcnt(2): drains B01 (covered by
//                                         MF32(0)'s ~1250cy), af landed, B23 flies
//   entry(t+1): vmcnt(0) drains B23 (covered by MF32(4)); barrier.
// B prefetch latency is never exposed; only 2x A-load latency (xb/hbuf L3-hot).
// af is a SINGLE 32-VGPR buffer (sequential reuse qm0->qm1): total regs stay
// ~112 VGPR + 128 AGPR = 240 <= 256 (2 waves/SIMD). launch_bounds stays (512,2).
// Accumulation order per acc element identical to R6 -> bit-identical numerics.
// [Ledger: R7 fences, R8 phases, R9 launch_bounds(512,4), R11 issue-order all
//  regressed. If this regresses too: restore R6 (597us) and conclude.]
template <int LDK, int NT>
__device__ __forceinline__ void gemm256g(const char* Abase, const unsigned (&aoff)[2][4],
                                         const bf16* gB0, char* smem, int tid,
                                         f32x4 (&acc)[8][4]) {
  const int wave = tid >> 6, lane = tid & 63;
  const int wn = wave & 3;
  const int fr = lane & 15, kl = lane >> 4;

  auto stageB = [&](int sel, int k0, int q) {
    gload_lds16(gB0 + (size_t)q * 64 * LDK + k0,
                smem + sel * 32768 + q * 8192 + wave * 1024);
  };

  frag8 af[4][2], bf0[2][2], bf1[2][2];

  auto rdB = [&](frag8 (&d)[2][2], const char* bB, int qn) {
#pragma unroll
    for (int f = 0; f < 2; ++f) {
      int row = wn * 64 + qn * 32 + f * 16 + fr;
#pragma unroll
      for (int ks = 0; ks < 2; ++ks)
        d[f][ks] = *(const frag8*)(bB + row * 128 + (((ks * 4 + kl) ^ (row & 7)) << 4));
    }
  };
  auto ldA = [&](int qm, int t) {
#pragma unroll
    for (int f = 0; f < 4; ++f) {
      const char* p = Abase + aoff[qm][f] + t * 128;
      af[f][0] = *(const frag8*)p;           // k-chunks kl, kl+4 (64B apart)
      af[f][1] = *(const frag8*)(p + 64);
    }
  };

  // 32-MFMA cluster: rows MO..MO+3 (x16), all 4 N-subtiles, K=64
#define MF32(MO)                                                                         \
  __builtin_amdgcn_s_setprio(1);                                                         \
  _Pragma("unroll") for (int m_ = 0; m_ < 4; ++m_) {                                     \
    _Pragma("unroll") for (int ks_ = 0; ks_ < 2; ++ks_) {                                \
      acc[(MO) + m_][0] = __builtin_amdgcn_mfma_f32_16x16x32_bf16(                       \
          af[m_][ks_], bf0[0][ks_], acc[(MO) + m_][0], 0, 0, 0);                         \
      acc[(MO) + m_][1] = __builtin_amdgcn_mfma_f32_16x16x32_bf16(                       \
          af[m_][ks_], bf0[1][ks_], acc[(MO) + m_][1], 0, 0, 0);                         \
      acc[(MO) + m_][2] = __builtin_amdgcn_mfma_f32_16x16x32_bf16(                       \
          af[m_][ks_], bf1[0][ks_], acc[(MO) + m_][2], 0, 0, 0);                         \
      acc[(MO) + m_][3] = __builtin_amdgcn_mfma_f32_16x16x32_bf16(                       \
          af[m_][ks_], bf1[1][ks_], acc[(MO) + m_][3], 0, 0, 0);                         \
    }                                                                                    \
  }                                                                                      \
  __builtin_amdgcn_s_setprio(0);

  // prologue: stage tile-0 B
  stageB(0, 0, 0); stageB(0, 0, 1); stageB(0, 0, 2); stageB(0, 0, 3);

#pragma unroll 1
  for (int t = 0; t < NT; ++t) {
    const char* bCur = smem + (t & 1) * 32768;
    const int ns = (t + 1) & 1, kn = (t + 1) * 64;
    const bool more = (t + 1 < NT);

    asm volatile("s_waitcnt vmcnt(0)" ::: "memory");   // t's B landed (covered by prior MF32)
    __builtin_amdgcn_s_barrier();
    asm volatile("" ::: "memory");

    ldA(0, t);                                   // oldest VMEM this tile
    asm volatile("" ::: "memory");               // pin: A before B stages
    if (more) { stageB(ns, kn, 0); stageB(ns, kn, 1); }
    asm volatile("" ::: "memory");
    rdB(bf0, bCur, 0);
    rdB(bf1, bCur, 1);
    MF32(0)                                      // waits vmcnt(2): B01 stays in flight

    ldA(1, t);                                   // reuse af regs after MF32(0)
    asm volatile("" ::: "memory");               // pin: A before B23
    if (more) { stageB(ns, kn, 2); stageB(ns, kn, 3); }
    asm volatile("" ::: "memory");
    MF32(4)                                      // waits vmcnt(2): B23 stays in flight
  }
#undef MF32
}

// ---------------- FFN1 grouped: h = silu(g)*u, merged wt13 ----------------
__global__ __launch_bounds__(512, 2)
void k_ffn1g(const bf16* __restrict__ xb, const bf16* __restrict__ wt13,
             bf16* __restrict__ hbuf, const int* __restrict__ ptok,
             const int* __restrict__ offs, const int* __restrict__ mtab) {
  extern __shared__ char smem[];
  int bx = (blockIdx.x & 7) * CPX + (blockIdx.x >> 3);   // XCD-chunked
  int entry = mtab[bx];
  if (entry < 0) return;
  int e = entry >> 16;
  int base = offs[e], nloc = offs[e + 1] - base;
  int m0 = (entry & 0xffff) * BM, n0 = blockIdx.y * 256;
  const bf16* wB = wt13 + (size_t)e * HID2 * DIM;
  bf16* hA = hbuf + (size_t)base * HID;

  int tid = threadIdx.x;
  int rr = tid >> 3, cc = tid & 7;
  int br = n0 + rr; if (br > HID2 - 1) br = HID2 - 1;
  const bf16* gB0 = wB + (size_t)br * DIM + (cc ^ (rr & 7)) * 8;

  int lane = tid & 63, wave = tid >> 6;
  int wm = wave >> 2, fr = lane & 15, kl = lane >> 4;
  unsigned aoff[2][4];
#pragma unroll
  for (int qm = 0; qm < 2; ++qm)
#pragma unroll
    for (int f = 0; f < 4; ++f) {
      int lr = m0 + wm * 128 + qm * 64 + f * 16 + fr;
      if (lr > nloc - 1) lr = nloc - 1;
      aoff[qm][f] = (unsigned)ptok[base + lr] * (DIM * 2) + kl * 16;
    }

  f32x4 acc[8][4];
  f32x4 zero = {0.f, 0.f, 0.f, 0.f};
#pragma unroll
  for (int a = 0; a < 8; ++a)
#pragma unroll
    for (int b = 0; b < 4; ++b) acc[a][b] = zero;

  gemm256g<DIM, DIM / 64>((const char*)xb, aoff, gB0, smem, tid, acc);

  int wn = wave & 3;
  int rj = (lane >> 4) * 4;
  int c0 = n0 + wn * 64;
#pragma unroll
  for (int m = 0; m < 8; ++m) {
#pragma unroll
    for (int j = 0; j < 4; ++j) {
      int rl = m0 + wm * 128 + m * 16 + rj + j;
      if (rl >= nloc) continue;
      bf16* hrow = hA + (size_t)rl * HID;
#pragma unroll
      for (int n = 0; n < 2; ++n) {
        int hcol = (c0 >> 1) + n * 16 + fr;
        if (hcol >= HID) continue;
        float g = acc[m][n][j], u = acc[m][n + 2][j];
        hrow[hcol] = __float2bfloat16(g / (1.f + __expf(-g)) * u);
      }
    }
  }
}

// ---------------- FFN2 grouped ----------------
// ATOMIC=1: out[tok] += w*(h@W2) via atomicAdd (fallback).
// ATOMIC=0: pbuf[base+rl] = bf16(w*(h@W2)) plain stores; reduced by k_reduce.
template <int ATOMIC>
__global__ __launch_bounds__(512, 2)
void k_ffn2g(const bf16* __restrict__ hbuf, const bf16* __restrict__ wt2,
             float* __restrict__ out, bf16* __restrict__ pbuf,
             const int* __restrict__ ptok, const float* __restrict__ pw,
             const int* __restrict__ offs, const int* __restrict__ mtab) {
  extern __shared__ char smem[];
  int bx = (blockIdx.x & 7) * CPX + (blockIdx.x >> 3);
  int entry = mtab[bx];
  if (entry < 0) return;
  int e = entry >> 16;
  int base = offs[e], nloc = offs[e + 1] - base;
  int m0 = (entry & 0xffff) * BM, n0 = blockIdx.y * 256;
  const bf16* wB = wt2 + (size_t)e * DIM * HID;
  const bf16* hA = hbuf + (size_t)base * HID;

  int tid = threadIdx.x;
  int rr = tid >> 3, cc = tid & 7;
  const bf16* gB0 = wB + (size_t)(n0 + rr) * HID + (cc ^ (rr & 7)) * 8;

  int lane = tid & 63, wave = tid >> 6;
  int wm = wave >> 2, fr = lane & 15, kl = lane >> 4;
  unsigned aoff[2][4];
#pragma unroll
  for (int qm = 0; qm < 2; ++qm)
#pragma unroll
    for (int f = 0; f < 4; ++f) {
      int lr = m0 + wm * 128 + qm * 64 + f * 16 + fr;
      if (lr > nloc - 1) lr = nloc - 1;
      aoff[qm][f] = (unsigned)lr * (HID * 2) + kl * 16;
    }

  f32x4 acc[8][4];
  f32x4 zero = {0.f, 0.f, 0.f, 0.f};
#pragma unroll
  for (int a = 0; a < 8; ++a)
#pragma unroll
    for (int b = 0; b < 4; ++b) acc[a][b] = zero;

  gemm256g<HID, HID / 64>((const char*)hA, aoff, gB0, smem, tid, acc);

  int wn = wave & 3;
  int rj = (lane >> 4) * 4;
#pragma unroll
  for (int m = 0; m < 8; ++m) {
#pragma unroll
    for (int j = 0; j < 4; ++j) {
      int rl = m0 + wm * 128 + m * 16 + rj + j;
      if (rl >= nloc) continue;
      float w = pw[base + rl];
      if (ATOMIC) {
        int tok = ptok[base + rl];
        float* orow = out + (size_t)tok * DIM + n0 + wn * 64 + fr;
#pragma unroll
        for (int n = 0; n < 4; ++n)
          atomicAdd(orow + n * 16, w * acc[m][n][j]);
      } else {
        bf16* prow = pbuf + (size_t)(base + rl) * DIM + n0 + wn * 64 + fr;
#pragma unroll
        for (int n = 0; n < 4; ++n)
          prow[n * 16] = __float2bfloat16(w * acc[m][n][j]);
      }
    }
  }
}

// ---------------- reduce: out[t] = pbuf[inv[2t]] + pbuf[inv[2t+1]] + pbuf[NPAIR+t] ----------------
__global__ void k_reduce(const bf16* __restrict__ pbuf, const int* __restrict__ inv,
                         float* __restrict__ out) {
  int t = blockIdx.x * 2 + (threadIdx.x >> 7);      // 2 tokens per 256-thread block
  int c = (threadIdx.x & 127) * 8;                  // 8 cols per thread
  int p0 = inv[t * 2], p1 = inv[t * 2 + 1];
  frag8 v0 = *(const frag8*)&pbuf[(size_t)p0 * DIM + c];
  frag8 v1 = *(const frag8*)&pbuf[(size_t)p1 * DIM + c];
  frag8 v2 = *(const frag8*)&pbuf[(size_t)(NPAIR + t) * DIM + c];
  float r[8];
#pragma unroll
  for (int j = 0; j < 8; ++j) r[j] = b2f(v0[j]) + b2f(v1[j]) + b2f(v2[j]);
  float4 lo = {r[0], r[1], r[2], r[3]};
  float4 hi = {r[4], r[5], r[6], r[7]};
  *(float4*)&out[(size_t)t * DIM + c]     = lo;
  *(float4*)&out[(size_t)t * DIM + c + 4] = hi;
}

extern "C" void kernel_launch(void* const* d_in, const int* in_sizes, int n_in,
                              void* d_out, int out_size, void* d_ws, size_t ws_size,
                              hipStream_t stream) {
  const float* x   = (const float*)d_in[0];
  const float* gw  = (const float*)d_in[1];
  const float* w1  = (const float*)d_in[2];
  const float* w2  = (const float*)d_in[3];
  const float* w3  = (const float*)d_in[4];
  const float* sw1 = (const float*)d_in[5];
  const float* sw2 = (const float*)d_in[6];
  const float* sw3 = (const float*)d_in[7];
  float* out = (float*)d_out;

  char* ws = (char*)d_ws;
  size_t off = 0;
  auto alloc = [&](size_t bytes) -> void* {
    void* p = ws + off;
    off += (bytes + 255) & ~(size_t)255;
    return p;
  };
  const size_t SZ  = (size_t)DIM * HID;
  const size_t S13 = (size_t)HID2 * DIM;

  // ---- meta ----
  int*   tke    = (int*)alloc((size_t)NPAIR * 4);
  float* tkw    = (float*)alloc((size_t)NPAIR * 4);
  int*   ptok   = (int*)alloc((size_t)NROW * 4);
  float* pw     = (float*)alloc((size_t)NROW * 4);
  int*   inv    = (int*)alloc((size_t)NPAIR * 4);
  int*   counts = (int*)alloc(16 * NE * 4);
  int*   offs   = (int*)alloc((NE + 2) * 4);
  int*   bcnt   = (int*)alloc((size_t)(NPAIR / 256) * NE * 4);
  int*   bbase  = (int*)alloc((size_t)(NPAIR / 256) * NE * 4);
  int*   mtab   = (int*)alloc(MAXMB * 4);
  bf16*  xb     = (bf16*)alloc((size_t)T_TOK * DIM * 2);

  // ---- grouped layout (~305 MB; proven to fit in rounds 2-7) ----
  bf16* wt13 = (bf16*)alloc(9 * S13 * 2);
  bf16* wt2b = (bf16*)alloc(9 * SZ * 2);
  bf16* hbuf = (bf16*)alloc((size_t)NROW * HID * 2);
  if (off > ws_size) return;   // visible failure signature

  // optional partial-sum buffer (+50 MB); fallback to atomic path if it won't fit
  bf16* pbuf = (bf16*)alloc((size_t)NROW * DIM * 2);
  bool usePbuf = (off <= ws_size);

  hipFuncSetAttribute((const void*)k_ffn1g, hipFuncAttributeMaxDynamicSharedMemorySize, 65536);
  hipFuncSetAttribute((const void*)k_ffn2g<0>, hipFuncAttributeMaxDynamicSharedMemorySize, 65536);
  hipFuncSetAttribute((const void*)k_ffn2g<1>, hipFuncAttributeMaxDynamicSharedMemorySize, 65536);

  // ---- frontend ----
  hipMemsetAsync(counts, 0, 16 * NE * sizeof(int), stream);
  if (!usePbuf)
    hipMemsetAsync(out, 0, (size_t)out_size * sizeof(float), stream);
  k_gate2<<<256, 256, 0, stream>>>(x, gw, xb, tke, tkw, counts);
  k_pcount<<<NPAIR / 256, 256, 0, stream>>>(tke, bcnt);
  k_pscan<<<1, 64, 0, stream>>>(counts, bcnt, offs, bbase, mtab);
  k_place<<<NPAIR / 256 + T_TOK / 256, 256, 0, stream>>>(tke, tkw, bbase, ptok, pw, inv);

  k_wt_all<<<dim3(688, 27), 256, 0, stream>>>(w1, w2, w3, sw1, sw2, sw3, wt13, wt2b);
  k_ffn1g<<<dim3(MAXMB, N1BLK), 512, 65536, stream>>>(xb, wt13, hbuf, ptok, offs, mtab);
  if (usePbuf) {
    k_ffn2g<0><<<dim3(MAXMB, DIM / 256), 512, 65536, stream>>>(hbuf, wt2b, out, pbuf,
                                                               ptok, pw, offs, mtab);
    k_reduce<<<T_TOK / 2, 256, 0, stream>>>(pbuf, inv, out);
  } else {
    k_ffn2g<1><<<dim3(MAXMB, DIM / 256), 512, 65536, stream>>>(hbuf, wt2b, out, pbuf,
                                                               ptok, pw, offs, mtab);
  }
}

// Round 6
// 566.007 us; speedup vs baseline: 2.1952x; 2.1657x over previous
//
#include <hip/hip_runtime.h>
#include <hip/hip_bf16.h>
#include <cstdint>
#include <cstddef>

#define T_TOK 8192
#define DIM   1024
#define HID   2752
#define HID2  (2 * HID)               // 5504 merged W1|W3 rows
#define NE    8
#define NKTOP 2
#define NPAIR (T_TOK * NKTOP)         // 16384 routed pairs
#define NROW  (NPAIR + T_TOK)         // 24576 rows incl shared group
#define BM    256
#define MAXMB (NPAIR / BM + NE + T_TOK / BM)   // 64+8+32 = 104 (13 per XCD)
#define CPX   (MAXMB / 8)
#define N1BLK ((HID2 + 255) / 256)    // 22

using bf16  = __hip_bfloat16;
using frag8 = __attribute__((ext_vector_type(8))) short;   // 8 bf16 (4 VGPRs)
using f32x4 = __attribute__((ext_vector_type(4))) float;   // MFMA accumulator

struct alignas(8) bf16x4_s { bf16 v[4]; };

__device__ __forceinline__ void gload_lds16(const void* g, void* lds) {
  __builtin_amdgcn_global_load_lds(
      (const __attribute__((address_space(1))) unsigned int*)g,
      (__attribute__((address_space(3))) unsigned int*)lds, 16, 0, 0);
}

__device__ __forceinline__ float b2f(short s) {
  union { float f; unsigned u; } x;
  x.u = ((unsigned)(unsigned short)s) << 16;
  return x.f;
}

// ---------------- gating body (runs as y==0 slice of k_wt_gate) ----------------
// 256 blocks x 4 waves; wave handles tokens strided by 1024. While computing
// the 8 logits it also writes the token's bf16 row (x is read exactly once).
__device__ __forceinline__ void gate_body(const float* __restrict__ x,
                                          const float* __restrict__ gw,
                                          bf16* __restrict__ xb,
                                          int* __restrict__ tke, float* __restrict__ tkw,
                                          int* __restrict__ counts, int bx) {
  __shared__ int lcnt[NE];
  int tid = threadIdx.x;
  if (tid < NE) lcnt[tid] = 0;
  __syncthreads();
  int lane = tid & 63, wid = tid >> 6;
  int wglob = bx * 4 + wid;
  for (int t = wglob; t < T_TOK; t += 1024) {
    float acc[NE];
#pragma unroll
    for (int e = 0; e < NE; ++e) acc[e] = 0.f;
#pragma unroll
    for (int it = 0; it < 4; ++it) {
      int d = it * 256 + lane * 4;
      float4 xv = *(const float4*)&x[(size_t)t * DIM + d];
      bf16x4_s o;
      o.v[0] = __float2bfloat16(xv.x);
      o.v[1] = __float2bfloat16(xv.y);
      o.v[2] = __float2bfloat16(xv.z);
      o.v[3] = __float2bfloat16(xv.w);
      *(bf16x4_s*)&xb[(size_t)t * DIM + d] = o;
#pragma unroll
      for (int e = 0; e < NE; ++e) {
        float4 gv = *(const float4*)&gw[(size_t)e * DIM + d];
        acc[e] += xv.x * gv.x + xv.y * gv.y + xv.z * gv.z + xv.w * gv.w;
      }
    }
#pragma unroll
    for (int e = 0; e < NE; ++e)
#pragma unroll
      for (int off = 32; off > 0; off >>= 1)
        acc[e] += __shfl_xor(acc[e], off, 64);
    if (lane == 0) {
      float mx = acc[0];
#pragma unroll
      for (int e = 1; e < NE; ++e) mx = fmaxf(mx, acc[e]);
      float p[NE], s = 0.f;
#pragma unroll
      for (int e = 0; e < NE; ++e) { p[e] = expf(acc[e] - mx); s += p[e]; }
      float inv = 1.f / s;
#pragma unroll
      for (int e = 0; e < NE; ++e) p[e] *= inv;
      int e0 = 0;
#pragma unroll
      for (int e = 1; e < NE; ++e) if (p[e] > p[e0]) e0 = e;
      int e1 = (e0 == 0) ? 1 : 0;
#pragma unroll
      for (int e = 0; e < NE; ++e) if (e != e0 && p[e] > p[e1]) e1 = e;
      tke[t * 2 + 0] = e0;  tkw[t * 2 + 0] = p[e0];
      tke[t * 2 + 1] = e1;  tkw[t * 2 + 1] = p[e1];
      atomicAdd(&lcnt[e0], 1);
      atomicAdd(&lcnt[e1], 1);
    }
  }
  __syncthreads();
  if (tid < NE) atomicAdd(&counts[tid * 16], lcnt[tid]);
}

// ---------------- deterministic pair placement ----------------
__global__ void k_pcount(const int* __restrict__ tke, int* __restrict__ bcnt) {
  __shared__ int lcnt[NE];
  int tid = threadIdx.x;
  if (tid < NE) lcnt[tid] = 0;
  __syncthreads();
  int e = tke[blockIdx.x * 256 + tid];
  atomicAdd(&lcnt[e], 1);
  __syncthreads();
  if (tid < NE) bcnt[blockIdx.x * NE + tid] = lcnt[tid];
}

__global__ void k_pscan(const int* __restrict__ counts, const int* __restrict__ bcnt,
                        int* __restrict__ offs, int* __restrict__ bbase,
                        int* __restrict__ mtab) {
  if (threadIdx.x == 0) {
    int s = 0;
    for (int e = 0; e < NE; ++e) { offs[e] = s; s += counts[e * 16]; }
    offs[NE] = s;                 // 16384 = start of shared group
    offs[NE + 1] = s + T_TOK;     // 24576
    int run[NE];
    for (int e = 0; e < NE; ++e) run[e] = offs[e];
    for (int b = 0; b < NPAIR / 256; ++b)
      for (int e = 0; e < NE; ++e) { bbase[b * NE + e] = run[e]; run[e] += bcnt[b * NE + e]; }
    int sl = 0;
    for (int e = 0; e < NE + 1; ++e) {       // 9 groups incl shared
      int cnt = offs[e + 1] - offs[e];
      int nb = (cnt + BM - 1) / BM;
      for (int b = 0; b < nb; ++b) mtab[sl++] = (e << 16) | b;
    }
    for (; sl < MAXMB; ++sl) mtab[sl] = -1;
  }
}

// pair placement (blocks 0..63) + shared-group identity init (blocks 64..95).
// also writes inverse map inv[pair i] = pos (for the reduce kernel)
__global__ void k_place(const int* __restrict__ tke, const float* __restrict__ tkw,
                        const int* __restrict__ bbase,
                        int* __restrict__ ptok, float* __restrict__ pw,
                        int* __restrict__ inv) {
  __shared__ int wcnt[4][NE];
  int tid = threadIdx.x;
  if (blockIdx.x >= NPAIR / 256) {           // identity tail (was k_ident)
    int i = (blockIdx.x - NPAIR / 256) * 256 + tid;
    ptok[NPAIR + i] = i;
    pw[NPAIR + i]   = 1.f;
    return;
  }
  int lane = tid & 63, w = tid >> 6;
  int i = blockIdx.x * 256 + tid;
  int e = tke[i];
  unsigned long long lower = (lane == 63) ? ~0ull >> 1 : ((1ull << lane) - 1);
  int rank = 0;
#pragma unroll
  for (int ex = 0; ex < NE; ++ex) {
    unsigned long long m = __ballot(e == ex);
    if (e == ex) rank = __popcll(m & lower);
    if (lane == 0) wcnt[w][ex] = __popcll(m);
  }
  __syncthreads();
  int wb = 0;
  for (int w2 = 0; w2 < w; ++w2) wb += wcnt[w2][e];
  int pos = bbase[blockIdx.x * NE + e] + wb + rank;
  ptok[pos] = i >> 1;
  pw[pos]   = tkw[i];
  inv[i]    = pos;
}

// ---------------- weight transpose-convert ----------------
// in fp32 [K][N] -> out bf16 rows (B^T layout) with optional merged-W13 row remap.
// mode 0: orow = h;  mode 1 (W1): orow = (h>>5)*64 + (h&31);  mode 2 (W3): +32
__device__ __forceinline__ void wt_tile2(const float* __restrict__ in, bf16* __restrict__ out,
                                         int K, int N, int nb, int kb, int mode) {
  __shared__ bf16 tile[64][65];
  int c16 = threadIdx.x >> 4;
  int r16 = threadIdx.x & 15;
#pragma unroll
  for (int it = 0; it < 4; ++it) {
    int k = it * 16 + c16;
    int n = r16 * 4;
    float4 v = *(const float4*)&in[(size_t)(kb + k) * N + nb + n];
    tile[n + 0][k] = __float2bfloat16(v.x);
    tile[n + 1][k] = __float2bfloat16(v.y);
    tile[n + 2][k] = __float2bfloat16(v.z);
    tile[n + 3][k] = __float2bfloat16(v.w);
  }
  __syncthreads();
#pragma unroll
  for (int it = 0; it < 4; ++it) {
    int n = it * 16 + c16;
    int k = r16 * 4;
    int h = nb + n;
    int orow = (mode == 0) ? h : ((h >> 5) * 64 + (h & 31) + (mode == 2 ? 32 : 0));
    bf16x4_s o;
    o.v[0] = tile[n][k + 0];
    o.v[1] = tile[n][k + 1];
    o.v[2] = tile[n][k + 2];
    o.v[3] = tile[n][k + 3];
    *(bf16x4_s*)&out[(size_t)orow * K + kb + k] = o;
  }
}

// one launch: y==0 -> gating (first-dispatched, hides under transpose work);
// y=1..27 -> 27 matrices: 0..7 w1, 8..15 w3, 16..23 w2, 24 sw1, 25 sw3, 26 sw2
__global__ void k_wt_gate(const float* __restrict__ w1, const float* __restrict__ w2,
                          const float* __restrict__ w3, const float* __restrict__ sw1,
                          const float* __restrict__ sw2, const float* __restrict__ sw3,
                          bf16* __restrict__ wt13, bf16* __restrict__ wt2,
                          const float* __restrict__ x, const float* __restrict__ gw,
                          bf16* __restrict__ xb, int* __restrict__ tke,
                          float* __restrict__ tkw, int* __restrict__ counts) {
  int m = blockIdx.y;
  int bx = blockIdx.x;
  if (m == 0) {
    if (bx < 256) gate_body(x, gw, xb, tke, tkw, counts, bx);
    return;
  }
  m -= 1;
  const size_t SZ = (size_t)DIM * HID;
  const size_t S13 = (size_t)HID2 * DIM;
  const float* src; bf16* dst; int K, N, mode;
  if (m < 8)       { src = w1 + (size_t)m * SZ;        dst = wt13 + (size_t)m * S13;        K = DIM; N = HID; mode = 1; }
  else if (m < 16) { src = w3 + (size_t)(m - 8) * SZ;  dst = wt13 + (size_t)(m - 8) * S13;  K = DIM; N = HID; mode = 2; }
  else if (m < 24) { src = w2 + (size_t)(m - 16) * SZ; dst = wt2 + (size_t)(m - 16) * SZ;   K = HID; N = DIM; mode = 0; }
  else if (m == 24){ src = sw1; dst = wt13 + 8 * S13; K = DIM; N = HID; mode = 1; }
  else if (m == 25){ src = sw3; dst = wt13 + 8 * S13; K = DIM; N = HID; mode = 2; }
  else             { src = sw2; dst = wt2 + 8 * SZ;   K = HID; N = DIM; mode = 0; }
  int nx = N / 64;
  wt_tile2(src, dst, K, N, (bx % nx) * 64, (bx / nx) * 64, mode);
}

// ---------------- 256x256x64 grouped GEMM core, 2-phase counted-vmcnt (R6) ----------------
// 512 threads = 8 waves (2M x 4N); wave tile 128x64; acc[8][4] f32x4.
// LDS (dynamic, 128KB): A: smem + sel*32768, B: smem + 65536 + sel*32768.
// T2 swizzle: 16B chunk c_phys = c_log ^ (row&7); staged via pre-swizzled source.
//
// Stage issue order per tile (need-ordered): A0,A2 | B0,B1 | B2,B3 | A1,A3
// Per K-tile t (2 barriers, 2 counted vmcnts, max 8 in flight):
//   entry: vmcnt(2)  -> t's A0,A2,B0-3 landed (t's A1,A3 may fly); barrier
//   Ph0:  stage t+1 A0,A2; rdA(qm0)+rdB(all); stage t+1 B0,B1; 32 MFMA
//   Ph1:  stage t+1 B2,B3; vmcnt(6) -> t's A1,A3 landed, t+1's 6 in flight; barrier;
//         rdA(qm1); 32 MFMA (B frags reused); stage t+1 A1,A3
// No end-barrier: t+1's entry barrier guarantees all waves finished t's LDS reads.
// [FINAL session ledger on this core: R7 fence graft, R8 4-phase graft,
//  R9 launch_bounds(512,4) reg-A, R11 reg-A-from-global, R12 issue-order-pinned
//  reg-A ALL regressed with understood mechanisms. 837 TF / 40% MfmaUtil is the
//  plateau for this grouped-GEMM structure in plain HIP. DO NOT MODIFY.]
template <int LDK, int NT>
__device__ __forceinline__ void gemm256(const bf16* const* gA, const bf16* gB0,
                                        char* smem, int tid, f32x4 (&acc)[8][4]) {
  const int wave = tid >> 6, lane = tid & 63;
  const int wm = wave >> 2, wn = wave & 3;
  const int fr = lane & 15, kl = lane >> 4;

  auto stageA = [&](int sel, int k0, int q) {
    gload_lds16(gA[q] + k0, smem + sel * 32768 + q * 8192 + wave * 1024);
  };
  auto stageB = [&](int sel, int k0, int q) {
    gload_lds16(gB0 + (size_t)q * 64 * LDK + k0,
                smem + 65536 + sel * 32768 + q * 8192 + wave * 1024);
  };

  frag8 af[4][2], bf0[2][2], bf1[2][2];

  auto rdA = [&](const char* bA, int qm) {
#pragma unroll
    for (int f = 0; f < 4; ++f) {
      int row = wm * 128 + qm * 64 + f * 16 + fr;
#pragma unroll
      for (int ks = 0; ks < 2; ++ks)
        af[f][ks] = *(const frag8*)(bA + row * 128 + (((ks * 4 + kl) ^ (row & 7)) << 4));
    }
  };
  auto rdB = [&](frag8 (&d)[2][2], const char* bB, int qn) {
#pragma unroll
    for (int f = 0; f < 2; ++f) {
      int row = wn * 64 + qn * 32 + f * 16 + fr;
#pragma unroll
      for (int ks = 0; ks < 2; ++ks)
        d[f][ks] = *(const frag8*)(bB + row * 128 + (((ks * 4 + kl) ^ (row & 7)) << 4));
    }
  };

  // 32-MFMA cluster: rows MO..MO+3 (x16), all 4 N-subtiles, K=64
#define MF32(MO)                                                                         \
  __builtin_amdgcn_s_setprio(1);                                                         \
  _Pragma("unroll") for (int m_ = 0; m_ < 4; ++m_) {                                     \
    _Pragma("unroll") for (int ks_ = 0; ks_ < 2; ++ks_) {                                \
      acc[(MO) + m_][0] = __builtin_amdgcn_mfma_f32_16x16x32_bf16(                       \
          af[m_][ks_], bf0[0][ks_], acc[(MO) + m_][0], 0, 0, 0);                         \
      acc[(MO) + m_][1] = __builtin_amdgcn_mfma_f32_16x16x32_bf16(                       \
          af[m_][ks_], bf0[1][ks_], acc[(MO) + m_][1], 0, 0, 0);                         \
      acc[(MO) + m_][2] = __builtin_amdgcn_mfma_f32_16x16x32_bf16(                       \
          af[m_][ks_], bf1[0][ks_], acc[(MO) + m_][2], 0, 0, 0);                         \
      acc[(MO) + m_][3] = __builtin_amdgcn_mfma_f32_16x16x32_bf16(                       \
          af[m_][ks_], bf1[1][ks_], acc[(MO) + m_][3], 0, 0, 0);                         \
    }                                                                                    \
  }                                                                                      \
  __builtin_amdgcn_s_setprio(0);

  // prologue: tile 0 in need-order A0,A2,B0,B1,B2,B3,A1,A3
  stageA(0, 0, 0); stageA(0, 0, 2);
  stageB(0, 0, 0); stageB(0, 0, 1); stageB(0, 0, 2); stageB(0, 0, 3);
  stageA(0, 0, 1); stageA(0, 0, 3);

#pragma unroll 1
  for (int t = 0; t < NT; ++t) {
    const char* aCur = smem + (t & 1) * 32768;
    const char* bCur = smem + 65536 + (t & 1) * 32768;
    const int ns = (t + 1) & 1, kn = (t + 1) * 64;
    const bool more = (t + 1 < NT);

    asm volatile("s_waitcnt vmcnt(2)" ::: "memory");   // t's first 6 landed
    __builtin_amdgcn_s_barrier();
    asm volatile("" ::: "memory");

    // Ph0
    if (more) { stageA(ns, kn, 0); stageA(ns, kn, 2); }
    rdA(aCur, 0);
    rdB(bf0, bCur, 0);
    rdB(bf1, bCur, 1);
    if (more) { stageB(ns, kn, 0); stageB(ns, kn, 1); }
    MF32(0)

    // Ph1
    if (more) {
      stageB(ns, kn, 2); stageB(ns, kn, 3);
      asm volatile("s_waitcnt vmcnt(6)" ::: "memory"); // t's A1,A3 landed; t+1's 6 fly
    } else {
      asm volatile("s_waitcnt vmcnt(0)" ::: "memory");
    }
    __builtin_amdgcn_s_barrier();
    asm volatile("" ::: "memory");
    rdA(aCur, 1);
    MF32(4)
    if (more) { stageA(ns, kn, 1); stageA(ns, kn, 3); }
  }
#undef MF32
}

// ---------------- FFN1 grouped: h = silu(g)*u, merged wt13 ----------------
__global__ __launch_bounds__(512, 2)
void k_ffn1g(const bf16* __restrict__ xb, const bf16* __restrict__ wt13,
             bf16* __restrict__ hbuf, const int* __restrict__ ptok,
             const int* __restrict__ offs, const int* __restrict__ mtab) {
  extern __shared__ char smem[];
  int bx = (blockIdx.x & 7) * CPX + (blockIdx.x >> 3);   // XCD-chunked
  int entry = mtab[bx];
  if (entry < 0) return;
  int e = entry >> 16;
  int base = offs[e], nloc = offs[e + 1] - base;
  int m0 = (entry & 0xffff) * BM, n0 = blockIdx.y * 256;
  const bf16* wB = wt13 + (size_t)e * HID2 * DIM;
  bf16* hA = hbuf + (size_t)base * HID;

  int tid = threadIdx.x;
  const bf16* gA[4];
  int rr = tid >> 3, cc = tid & 7;
#pragma unroll
  for (int q = 0; q < 4; ++q) {
    int r = q * 64 + rr;
    int c = cc ^ (r & 7);
    int lr = m0 + r; if (lr > nloc - 1) lr = nloc - 1;
    gA[q] = xb + (size_t)ptok[base + lr] * DIM + c * 8;
  }
  int br = n0 + rr; if (br > HID2 - 1) br = HID2 - 1;
  const bf16* gB0 = wB + (size_t)br * DIM + (cc ^ (rr & 7)) * 8;

  f32x4 acc[8][4];
  f32x4 zero = {0.f, 0.f, 0.f, 0.f};
#pragma unroll
  for (int a = 0; a < 8; ++a)
#pragma unroll
    for (int b = 0; b < 4; ++b) acc[a][b] = zero;

  gemm256<DIM, DIM / 64>(gA, gB0, smem, tid, acc);

  int lane = tid & 63, wave = tid >> 6;
  int wm = wave >> 2, wn = wave & 3;
  int fr = lane & 15, rj = (lane >> 4) * 4;
  int c0 = n0 + wn * 64;
#pragma unroll
  for (int m = 0; m < 8; ++m) {
#pragma unroll
    for (int j = 0; j < 4; ++j) {
      int rl = m0 + wm * 128 + m * 16 + rj + j;
      if (rl >= nloc) continue;
      bf16* hrow = hA + (size_t)rl * HID;
#pragma unroll
      for (int n = 0; n < 2; ++n) {
        int hcol = (c0 >> 1) + n * 16 + fr;
        if (hcol >= HID) continue;
        float g = acc[m][n][j], u = acc[m][n + 2][j];
        hrow[hcol] = __float2bfloat16(g / (1.f + __expf(-g)) * u);
      }
    }
  }
}

// ---------------- FFN2 grouped ----------------
// ATOMIC=1: out[tok] += w*(h@W2) via atomicAdd (fallback).
// ATOMIC=0: pbuf[base+rl] = bf16(w*(h@W2)) plain stores; reduced by k_reduce.
template <int ATOMIC>
__global__ __launch_bounds__(512, 2)
void k_ffn2g(const bf16* __restrict__ hbuf, const bf16* __restrict__ wt2,
             float* __restrict__ out, bf16* __restrict__ pbuf,
             const int* __restrict__ ptok, const float* __restrict__ pw,
             const int* __restrict__ offs, const int* __restrict__ mtab) {
  extern __shared__ char smem[];
  int bx = (blockIdx.x & 7) * CPX + (blockIdx.x >> 3);
  int entry = mtab[bx];
  if (entry < 0) return;
  int e = entry >> 16;
  int base = offs[e], nloc = offs[e + 1] - base;
  int m0 = (entry & 0xffff) * BM, n0 = blockIdx.y * 256;
  const bf16* wB = wt2 + (size_t)e * DIM * HID;
  const bf16* hA = hbuf + (size_t)base * HID;

  int tid = threadIdx.x;
  const bf16* gA[4];
  int rr = tid >> 3, cc = tid & 7;
#pragma unroll
  for (int q = 0; q < 4; ++q) {
    int r = q * 64 + rr;
    int c = cc ^ (r & 7);
    int lr = m0 + r; if (lr > nloc - 1) lr = nloc - 1;
    gA[q] = hA + (size_t)lr * HID + c * 8;
  }
  const bf16* gB0 = wB + (size_t)(n0 + rr) * HID + (cc ^ (rr & 7)) * 8;

  f32x4 acc[8][4];
  f32x4 zero = {0.f, 0.f, 0.f, 0.f};
#pragma unroll
  for (int a = 0; a < 8; ++a)
#pragma unroll
    for (int b = 0; b < 4; ++b) acc[a][b] = zero;

  gemm256<HID, HID / 64>(gA, gB0, smem, tid, acc);

  int lane = tid & 63, wave = tid >> 6;
  int wm = wave >> 2, wn = wave & 3;
  int fr = lane & 15, rj = (lane >> 4) * 4;
#pragma unroll
  for (int m = 0; m < 8; ++m) {
#pragma unroll
    for (int j = 0; j < 4; ++j) {
      int rl = m0 + wm * 128 + m * 16 + rj + j;
      if (rl >= nloc) continue;
      float w = pw[base + rl];
      if (ATOMIC) {
        int tok = ptok[base + rl];
        float* orow = out + (size_t)tok * DIM + n0 + wn * 64 + fr;
#pragma unroll
        for (int n = 0; n < 4; ++n)
          atomicAdd(orow + n * 16, w * acc[m][n][j]);
      } else {
        bf16* prow = pbuf + (size_t)(base + rl) * DIM + n0 + wn * 64 + fr;
#pragma unroll
        for (int n = 0; n < 4; ++n)
          prow[n * 16] = __float2bfloat16(w * acc[m][n][j]);
      }
    }
  }
}

// ---------------- reduce: out[t] = pbuf[inv[2t]] + pbuf[inv[2t+1]] + pbuf[NPAIR+t] ----------------
__global__ void k_reduce(const bf16* __restrict__ pbuf, const int* __restrict__ inv,
                         float* __restrict__ out) {
  int t = blockIdx.x * 2 + (threadIdx.x >> 7);      // 2 tokens per 256-thread block
  int c = (threadIdx.x & 127) * 8;                  // 8 cols per thread
  int p0 = inv[t * 2], p1 = inv[t * 2 + 1];
  frag8 v0 = *(const frag8*)&pbuf[(size_t)p0 * DIM + c];
  frag8 v1 = *(const frag8*)&pbuf[(size_t)p1 * DIM + c];
  frag8 v2 = *(const frag8*)&pbuf[(size_t)(NPAIR + t) * DIM + c];
  float r[8];
#pragma unroll
  for (int j = 0; j < 8; ++j) r[j] = b2f(v0[j]) + b2f(v1[j]) + b2f(v2[j]);
  float4 lo = {r[0], r[1], r[2], r[3]};
  float4 hi = {r[4], r[5], r[6], r[7]};
  *(float4*)&out[(size_t)t * DIM + c]     = lo;
  *(float4*)&out[(size_t)t * DIM + c + 4] = hi;
}

extern "C" void kernel_launch(void* const* d_in, const int* in_sizes, int n_in,
                              void* d_out, int out_size, void* d_ws, size_t ws_size,
                              hipStream_t stream) {
  const float* x   = (const float*)d_in[0];
  const float* gw  = (const float*)d_in[1];
  const float* w1  = (const float*)d_in[2];
  const float* w2  = (const float*)d_in[3];
  const float* w3  = (const float*)d_in[4];
  const float* sw1 = (const float*)d_in[5];
  const float* sw2 = (const float*)d_in[6];
  const float* sw3 = (const float*)d_in[7];
  float* out = (float*)d_out;

  char* ws = (char*)d_ws;
  size_t off = 0;
  auto alloc = [&](size_t bytes) -> void* {
    void* p = ws + off;
    off += (bytes + 255) & ~(size_t)255;
    return p;
  };
  const size_t SZ  = (size_t)DIM * HID;
  const size_t S13 = (size_t)HID2 * DIM;

  // ---- meta ----
  int*   tke    = (int*)alloc((size_t)NPAIR * 4);
  float* tkw    = (float*)alloc((size_t)NPAIR * 4);
  int*   ptok   = (int*)alloc((size_t)NROW * 4);
  float* pw     = (float*)alloc((size_t)NROW * 4);
  int*   inv    = (int*)alloc((size_t)NPAIR * 4);
  int*   counts = (int*)alloc(16 * NE * 4);
  int*   offs   = (int*)alloc((NE + 2) * 4);
  int*   bcnt   = (int*)alloc((size_t)(NPAIR / 256) * NE * 4);
  int*   bbase  = (int*)alloc((size_t)(NPAIR / 256) * NE * 4);
  int*   mtab   = (int*)alloc(MAXMB * 4);
  bf16*  xb     = (bf16*)alloc((size_t)T_TOK * DIM * 2);

  // ---- grouped layout (~305 MB; proven to fit in rounds 2-7) ----
  bf16* wt13 = (bf16*)alloc(9 * S13 * 2);
  bf16* wt2b = (bf16*)alloc(9 * SZ * 2);
  bf16* hbuf = (bf16*)alloc((size_t)NROW * HID * 2);
  if (off > ws_size) return;   // visible failure signature

  // optional partial-sum buffer (+50 MB); fallback to atomic path if it won't fit
  bf16* pbuf = (bf16*)alloc((size_t)NROW * DIM * 2);
  bool usePbuf = (off <= ws_size);

  hipFuncSetAttribute((const void*)k_ffn1g, hipFuncAttributeMaxDynamicSharedMemorySize, 131072);
  hipFuncSetAttribute((const void*)k_ffn2g<0>, hipFuncAttributeMaxDynamicSharedMemorySize, 131072);
  hipFuncSetAttribute((const void*)k_ffn2g<1>, hipFuncAttributeMaxDynamicSharedMemorySize, 131072);

  // ---- frontend ----
  hipMemsetAsync(counts, 0, 16 * NE * sizeof(int), stream);
  if (!usePbuf)
    hipMemsetAsync(out, 0, (size_t)out_size * sizeof(float), stream);
  // merged: y==0 slice = gating (dispatched first, hides under transpose blocks)
  k_wt_gate<<<dim3(688, 28), 256, 0, stream>>>(w1, w2, w3, sw1, sw2, sw3, wt13, wt2b,
                                               x, gw, xb, tke, tkw, counts);
  k_pcount<<<NPAIR / 256, 256, 0, stream>>>(tke, bcnt);
  k_pscan<<<1, 64, 0, stream>>>(counts, bcnt, offs, bbase, mtab);
  k_place<<<NPAIR / 256 + T_TOK / 256, 256, 0, stream>>>(tke, tkw, bbase, ptok, pw, inv);

  k_ffn1g<<<dim3(MAXMB, N1BLK), 512, 131072, stream>>>(xb, wt13, hbuf, ptok, offs, mtab);
  if (usePbuf) {
    k_ffn2g<0><<<dim3(MAXMB, DIM / 256), 512, 131072, stream>>>(hbuf, wt2b, out, pbuf,
                                                                ptok, pw, offs, mtab);
    k_reduce<<<T_TOK / 2, 256, 0, stream>>>(pbuf, inv, out);
  } else {
    k_ffn2g<1><<<dim3(MAXMB, DIM / 256), 512, 131072, stream>>>(hbuf, wt2b, out, pbuf,
                                                                ptok, pw, offs, mtab);
  }
}